// Round 1
// baseline (165.257 us; speedup 1.0000x reference)
//
#include <hip/hip_runtime.h>
#include <hip/hip_bf16.h>
#include <stdint.h>

typedef __bf16 bf16;
typedef __attribute__((ext_vector_type(8))) __bf16 bf16x8;
typedef __attribute__((ext_vector_type(4))) float f32x4;

#define GLOAD16(gsrc, ldst)                                              \
  __builtin_amdgcn_global_load_lds(                                      \
      (const __attribute__((address_space(1))) unsigned int*)(gsrc),     \
      (__attribute__((address_space(3))) unsigned int*)(ldst), 16, 0, 0)

static constexpr int T_LEN = 4096;
static constexpr int WIN = 16;
static constexpr int WSZ = 2 * WIN + 1;  // 33

__device__ __forceinline__ bf16x8 cvt8(float4 a, float4 b) {
  bf16x8 o;
  o[0] = (bf16)a.x; o[1] = (bf16)a.y; o[2] = (bf16)a.z; o[3] = (bf16)a.w;
  o[4] = (bf16)b.x; o[5] = (bf16)b.y; o[6] = (bf16)b.z; o[7] = (bf16)b.w;
  return o;
}

// ---- cast x (fp32 -> bf16), 8 elems/thread, 8192*512 total ----
__global__ __launch_bounds__(256) void cast_x_kernel(const float* __restrict__ x,
                                                     bf16* __restrict__ xb) {
  int i = blockIdx.x * 256 + threadIdx.x;  // 524288 threads
  const float4* s4 = (const float4*)x + (size_t)i * 2;
  ((bf16x8*)xb)[i] = cvt8(s4[0], s4[1]);
}

// ---- cast + pack Wq,Wk,Wv -> wqkv[1536][512], Wp -> wpb[512][512] ----
__global__ __launch_bounds__(256) void cast_w_kernel(const float* __restrict__ wq,
                                                     const float* __restrict__ wk,
                                                     const float* __restrict__ wv,
                                                     const float* __restrict__ wp,
                                                     bf16* __restrict__ wqkv,
                                                     bf16* __restrict__ wpb) {
  int i = blockIdx.x * 256 + threadIdx.x;  // 131072 threads (4 * 512*512/8)
  int which = i >> 15;                     // 32768 groups of 8 per matrix
  int j = i & 32767;
  const float* src = (which == 0) ? wq : (which == 1) ? wk : (which == 2) ? wv : wp;
  bf16* dst = (which < 3) ? (wqkv + (size_t)which * 512 * 512) : wpb;
  const float4* s4 = (const float4*)src + (size_t)j * 2;
  ((bf16x8*)dst)[j] = cvt8(s4[0], s4[1]);
}

// ---- GEMM: C[m][n] = sum_k A[m][k] * Bw[n][k]  (A: Mx512 bf16, Bw: Nx512 bf16 row-major)
// EPI=0: store bf16 into Cb with leading dim ldc
// EPI=1: store fp32 Cf[m*512+n] = acc + Xres[m*512+n]   (residual)
template <int EPI>
__global__ __launch_bounds__(256) void gemm_bt_kernel(const bf16* __restrict__ A,
                                                      const bf16* __restrict__ Bw,
                                                      bf16* __restrict__ Cb, int ldc,
                                                      float* __restrict__ Cf,
                                                      const float* __restrict__ Xres,
                                                      int NB) {
  constexpr int K = 512, BK = 32;
  __shared__ __align__(16) bf16 As[128 * BK];
  __shared__ __align__(16) bf16 Bs[128 * BK];
  const int tid = threadIdx.x;
  const int l = tid & 63;
  const int w = tid >> 6;
  const int m0 = (blockIdx.x / NB) * 128;
  const int n0 = (blockIdx.x % NB) * 128;
  const int arow = tid >> 2;
  const int acol = (tid & 3) * 8;
  const bf16* Ag = A + (size_t)(m0 + arow) * K + acol;
  const bf16* Bg = Bw + (size_t)(n0 + arow) * K + acol;

  const f32x4 zero = {0.f, 0.f, 0.f, 0.f};
  f32x4 acc[4][4];
#pragma unroll
  for (int i = 0; i < 4; ++i)
#pragma unroll
    for (int j = 0; j < 4; ++j) acc[i][j] = zero;

  const int wm = (w >> 1) * 64;
  const int wn = (w & 1) * 64;
  const int frow = l & 15;
  const int fcol = (l >> 4) * 8;

  for (int k0 = 0; k0 < K; k0 += BK) {
    GLOAD16(Ag + k0,           &As[tid * 8]);
    GLOAD16(Ag + 64 * K + k0,  &As[tid * 8 + 2048]);
    GLOAD16(Bg + k0,           &Bs[tid * 8]);
    GLOAD16(Bg + 64 * K + k0,  &Bs[tid * 8 + 2048]);
    __syncthreads();
    bf16x8 af[4], bfr[4];
#pragma unroll
    for (int mi = 0; mi < 4; ++mi)
      af[mi] = *(const bf16x8*)&As[(wm + mi * 16 + frow) * BK + fcol];
#pragma unroll
    for (int ni = 0; ni < 4; ++ni)
      bfr[ni] = *(const bf16x8*)&Bs[(wn + ni * 16 + frow) * BK + fcol];
#pragma unroll
    for (int mi = 0; mi < 4; ++mi)
#pragma unroll
      for (int ni = 0; ni < 4; ++ni)
        acc[mi][ni] = __builtin_amdgcn_mfma_f32_16x16x32_bf16(af[mi], bfr[ni], acc[mi][ni], 0, 0, 0);
    __syncthreads();
  }

  // C/D layout: col = lane&15, row = (lane>>4)*4 + reg
  const int r0 = (l >> 4) * 4;
  const int c0 = l & 15;
#pragma unroll
  for (int mi = 0; mi < 4; ++mi) {
#pragma unroll
    for (int ni = 0; ni < 4; ++ni) {
      int row = m0 + wm + mi * 16 + r0;
      int col = n0 + wn + ni * 16 + c0;
#pragma unroll
      for (int r = 0; r < 4; ++r) {
        if (EPI == 0) {
          Cb[(size_t)(row + r) * ldc + col] = (bf16)acc[mi][ni][r];
        } else {
          size_t o = (size_t)(row + r) * 512 + col;
          Cf[o] = acc[mi][ni][r] + Xres[o];
        }
      }
    }
  }
}

// ---- local attention: thread per (b,t,h). qkv rows: [q(512) | k(512) | v(512)] ----
__global__ __launch_bounds__(256) void attn_kernel(const bf16* __restrict__ qkv,
                                                   bf16* __restrict__ aout) {
  __shared__ float Sl[256][WSZ];
  const int tid = threadIdx.x;
  const int idx = blockIdx.x * 256 + tid;  // 65536 = 8192*8
  const int h = idx >> 13;
  const int bt = idx & 8191;
  const int t = bt & (T_LEN - 1);
  const int base = bt - t;  // b*T
  const bf16* qrow = qkv + (size_t)bt * 1536 + h * 64;
  bf16x8 q8[8];
#pragma unroll
  for (int i = 0; i < 8; ++i) q8[i] = ((const bf16x8*)qrow)[i];
  const float scale = 0.125f;  // 64^-0.5

#pragma unroll 1
  for (int w = 0; w < WSZ; ++w) {
    int pos = t + w - WIN;
    bool valid = (pos >= 0) && (pos < T_LEN);
    int pc = min(max(pos, 0), T_LEN - 1);
    const bf16* krow = qkv + (size_t)(base + pc) * 1536 + 512 + h * 64;
    float acc = 0.f;
#pragma unroll
    for (int i = 0; i < 8; ++i) {
      bf16x8 k8 = ((const bf16x8*)krow)[i];
#pragma unroll
      for (int e = 0; e < 8; ++e) acc += (float)q8[i][e] * (float)k8[e];
    }
    Sl[tid][w] = valid ? acc * scale : -1e30f;
  }

  float m = -1e30f;
#pragma unroll 1
  for (int w = 0; w < WSZ; ++w) m = fmaxf(m, Sl[tid][w]);
  float sum = 0.f;
#pragma unroll 1
  for (int w = 0; w < WSZ; ++w) {
    float p = __expf(Sl[tid][w] - m);
    Sl[tid][w] = p;
    sum += p;
  }
  float inv = 1.f / sum;

  float o[64];
#pragma unroll
  for (int d = 0; d < 64; ++d) o[d] = 0.f;
#pragma unroll 1
  for (int w = 0; w < WSZ; ++w) {
    int pos = t + w - WIN;
    int pc = min(max(pos, 0), T_LEN - 1);
    const bf16* vrow = qkv + (size_t)(base + pc) * 1536 + 1024 + h * 64;
    float pw = Sl[tid][w];
#pragma unroll
    for (int i = 0; i < 8; ++i) {
      bf16x8 v8 = ((const bf16x8*)vrow)[i];
#pragma unroll
      for (int e = 0; e < 8; ++e) o[i * 8 + e] += pw * (float)v8[e];
    }
  }
  bf16* orow = aout + (size_t)bt * 512 + h * 64;
#pragma unroll
  for (int i = 0; i < 8; ++i) {
    bf16x8 ov;
#pragma unroll
    for (int e = 0; e < 8; ++e) ov[e] = (bf16)(o[i * 8 + e] * inv);
    ((bf16x8*)orow)[i] = ov;
  }
}

// ---- in-place LayerNorm, one wave per 512-wide row ----
__global__ __launch_bounds__(256) void ln_kernel(float* __restrict__ y,
                                                 const float* __restrict__ gamma,
                                                 const float* __restrict__ beta) {
  const int tid = threadIdx.x;
  const int l = tid & 63;
  const int row = blockIdx.x * 4 + (tid >> 6);
  float* p = y + (size_t)row * 512 + l * 8;
  float4 a = *(const float4*)(p);
  float4 b = *(const float4*)(p + 4);
  float s = a.x + a.y + a.z + a.w + b.x + b.y + b.z + b.w;
  float ss = a.x * a.x + a.y * a.y + a.z * a.z + a.w * a.w +
             b.x * b.x + b.y * b.y + b.z * b.z + b.w * b.w;
#pragma unroll
  for (int off = 32; off > 0; off >>= 1) {
    s += __shfl_xor(s, off);
    ss += __shfl_xor(ss, off);
  }
  float mu = s * (1.f / 512.f);
  float var = ss * (1.f / 512.f) - mu * mu;
  float rs = rsqrtf(var + 1e-5f);
  float4 g0 = *(const float4*)(gamma + l * 8);
  float4 g1 = *(const float4*)(gamma + l * 8 + 4);
  float4 b0 = *(const float4*)(beta + l * 8);
  float4 b1 = *(const float4*)(beta + l * 8 + 4);
  float4 o0, o1;
  o0.x = g0.x * (a.x - mu) * rs + b0.x;
  o0.y = g0.y * (a.y - mu) * rs + b0.y;
  o0.z = g0.z * (a.z - mu) * rs + b0.z;
  o0.w = g0.w * (a.w - mu) * rs + b0.w;
  o1.x = g1.x * (b.x - mu) * rs + b1.x;
  o1.y = g1.y * (b.y - mu) * rs + b1.y;
  o1.z = g1.z * (b.z - mu) * rs + b1.z;
  o1.w = g1.w * (b.w - mu) * rs + b1.w;
  *(float4*)(p) = o0;
  *(float4*)(p + 4) = o1;
}

extern "C" void kernel_launch(void* const* d_in, const int* in_sizes, int n_in,
                              void* d_out, int out_size, void* d_ws, size_t ws_size,
                              hipStream_t stream) {
  const float* x  = (const float*)d_in[0];
  const float* Wq = (const float*)d_in[1];
  const float* Wk = (const float*)d_in[2];
  const float* Wv = (const float*)d_in[3];
  const float* Wp = (const float*)d_in[4];
  const float* g  = (const float*)d_in[5];
  const float* be = (const float*)d_in[6];
  float* out = (float*)d_out;

  char* ws = (char*)d_ws;
  bf16* xb   = (bf16*)(ws);                                   // 8,388,608 B
  bf16* wqkv = (bf16*)(ws + 8388608);                         // 1,572,864 B
  bf16* wpb  = (bf16*)(ws + 8388608 + 1572864);               //   524,288 B
  bf16* qkv  = (bf16*)(ws + 8388608 + 1572864 + 524288);      // 25,165,824 B
  bf16* aout = (bf16*)(ws + 8388608 + 1572864 + 524288 + 25165824);  // 8,388,608 B

  cast_x_kernel<<<2048, 256, 0, stream>>>(x, xb);
  cast_w_kernel<<<512, 256, 0, stream>>>(Wq, Wk, Wv, Wp, wqkv, wpb);
  // QKV: M=8192, N=1536 -> 64 x 12 tiles
  gemm_bt_kernel<0><<<64 * 12, 256, 0, stream>>>(xb, wqkv, qkv, 1536, nullptr, nullptr, 12);
  attn_kernel<<<256, 256, 0, stream>>>(qkv, aout);
  // proj + residual: M=8192, N=512 -> 64 x 4 tiles
  gemm_bt_kernel<1><<<64 * 4, 256, 0, stream>>>(aout, wpb, nullptr, 0, out, x, 4);
  ln_kernel<<<2048, 256, 0, stream>>>(out, g, be);
}

// Round 2
// 114.530 us; speedup vs baseline: 1.4429x; 1.4429x over previous
//
#include <hip/hip_runtime.h>
#include <hip/hip_bf16.h>
#include <stdint.h>

typedef __bf16 bf16;
typedef __attribute__((ext_vector_type(8))) __bf16 bf16x8;
typedef __attribute__((ext_vector_type(4))) float f32x4;

#define GLOAD16(gsrc, ldst)                                              \
  __builtin_amdgcn_global_load_lds(                                      \
      (const __attribute__((address_space(1))) unsigned int*)(gsrc),     \
      (__attribute__((address_space(3))) unsigned int*)(ldst), 16, 0, 0)

static constexpr int T_LEN = 4096;
static constexpr int WIN = 16;
static constexpr int WSZ = 2 * WIN + 1;  // 33

__device__ __forceinline__ bf16x8 cvt8(float4 a, float4 b) {
  bf16x8 o;
  o[0] = (bf16)a.x; o[1] = (bf16)a.y; o[2] = (bf16)a.z; o[3] = (bf16)a.w;
  o[4] = (bf16)b.x; o[5] = (bf16)b.y; o[6] = (bf16)b.z; o[7] = (bf16)b.w;
  return o;
}

// ---- cast x (fp32 -> bf16), 8 elems/thread, 8192*512 total ----
__global__ __launch_bounds__(256) void cast_x_kernel(const float* __restrict__ x,
                                                     bf16* __restrict__ xb) {
  int i = blockIdx.x * 256 + threadIdx.x;  // 524288 threads
  const float4* s4 = (const float4*)x + (size_t)i * 2;
  ((bf16x8*)xb)[i] = cvt8(s4[0], s4[1]);
}

// ---- cast + pack Wq,Wk,Wv -> wqkv[1536][512], Wp -> wpb[512][512] ----
__global__ __launch_bounds__(256) void cast_w_kernel(const float* __restrict__ wq,
                                                     const float* __restrict__ wk,
                                                     const float* __restrict__ wv,
                                                     const float* __restrict__ wp,
                                                     bf16* __restrict__ wqkv,
                                                     bf16* __restrict__ wpb) {
  int i = blockIdx.x * 256 + threadIdx.x;  // 131072 threads (4 * 512*512/8)
  int which = i >> 15;                     // 32768 groups of 8 per matrix
  int j = i & 32767;
  const float* src = (which == 0) ? wq : (which == 1) ? wk : (which == 2) ? wv : wp;
  bf16* dst = (which < 3) ? (wqkv + (size_t)which * 512 * 512) : wpb;
  const float4* s4 = (const float4*)src + (size_t)j * 2;
  ((bf16x8*)dst)[j] = cvt8(s4[0], s4[1]);
}

// ---- GEMM: C[m][n] = sum_k A[m][k] * Bw[n][k]  (A: Mx512 bf16, Bw: Nx512 bf16 row-major)
// EPI=0: store bf16 into Cb with leading dim ldc
// EPI=1: store fp32 Cf[m*512+n] = acc + Xres[m*512+n]   (residual)
template <int EPI>
__global__ __launch_bounds__(256) void gemm_bt_kernel(const bf16* __restrict__ A,
                                                      const bf16* __restrict__ Bw,
                                                      bf16* __restrict__ Cb, int ldc,
                                                      float* __restrict__ Cf,
                                                      const float* __restrict__ Xres,
                                                      int NB) {
  constexpr int K = 512, BK = 32;
  __shared__ __align__(16) bf16 As[128 * BK];
  __shared__ __align__(16) bf16 Bs[128 * BK];
  const int tid = threadIdx.x;
  const int l = tid & 63;
  const int w = tid >> 6;
  const int m0 = (blockIdx.x / NB) * 128;
  const int n0 = (blockIdx.x % NB) * 128;
  const int arow = tid >> 2;
  const int acol = (tid & 3) * 8;
  const bf16* Ag = A + (size_t)(m0 + arow) * K + acol;
  const bf16* Bg = Bw + (size_t)(n0 + arow) * K + acol;

  const f32x4 zero = {0.f, 0.f, 0.f, 0.f};
  f32x4 acc[4][4];
#pragma unroll
  for (int i = 0; i < 4; ++i)
#pragma unroll
    for (int j = 0; j < 4; ++j) acc[i][j] = zero;

  const int wm = (w >> 1) * 64;
  const int wn = (w & 1) * 64;
  const int frow = l & 15;
  const int fcol = (l >> 4) * 8;

  for (int k0 = 0; k0 < K; k0 += BK) {
    GLOAD16(Ag + k0,           &As[tid * 8]);
    GLOAD16(Ag + 64 * K + k0,  &As[tid * 8 + 2048]);
    GLOAD16(Bg + k0,           &Bs[tid * 8]);
    GLOAD16(Bg + 64 * K + k0,  &Bs[tid * 8 + 2048]);
    __syncthreads();
    bf16x8 af[4], bfr[4];
#pragma unroll
    for (int mi = 0; mi < 4; ++mi)
      af[mi] = *(const bf16x8*)&As[(wm + mi * 16 + frow) * BK + fcol];
#pragma unroll
    for (int ni = 0; ni < 4; ++ni)
      bfr[ni] = *(const bf16x8*)&Bs[(wn + ni * 16 + frow) * BK + fcol];
#pragma unroll
    for (int mi = 0; mi < 4; ++mi)
#pragma unroll
      for (int ni = 0; ni < 4; ++ni)
        acc[mi][ni] = __builtin_amdgcn_mfma_f32_16x16x32_bf16(af[mi], bfr[ni], acc[mi][ni], 0, 0, 0);
    __syncthreads();
  }

  // C/D layout: col = lane&15, row = (lane>>4)*4 + reg
  const int r0 = (l >> 4) * 4;
  const int c0 = l & 15;
#pragma unroll
  for (int mi = 0; mi < 4; ++mi) {
#pragma unroll
    for (int ni = 0; ni < 4; ++ni) {
      int row = m0 + wm + mi * 16 + r0;
      int col = n0 + wn + ni * 16 + c0;
#pragma unroll
      for (int r = 0; r < 4; ++r) {
        if (EPI == 0) {
          Cb[(size_t)(row + r) * ldc + col] = (bf16)acc[mi][ni][r];
        } else {
          size_t o = (size_t)(row + r) * 512 + col;
          Cf[o] = acc[mi][ni][r] + Xres[o];
        }
      }
    }
  }
}

// ---- local attention: 8 lanes per (b,t,h) item, 8 dims each ----
// qkv rows: [q(512) | k(512) | v(512)], head h occupies dims h*64..h*64+63
__global__ __launch_bounds__(256) void attn_kernel(const bf16* __restrict__ qkv,
                                                   bf16* __restrict__ aout) {
  const int g = blockIdx.x * 256 + threadIdx.x;  // 524288 = 65536 items * 8
  const int item = g >> 3;
  const int dsub = g & 7;          // which 8-dim slice of the 64-dim head
  const int h = item >> 13;
  const int bt = item & 8191;
  const int t = bt & (T_LEN - 1);
  const int base = bt - t;         // b*T

  const size_t qoff = (size_t)bt * 1536 + h * 64 + dsub * 8;
  bf16x8 q8 = *(const bf16x8*)(qkv + qoff);
  const float scale = 0.125f;      // 64^-0.5

  float s[WSZ];
#pragma unroll
  for (int w = 0; w < WSZ; ++w) {
    int pos = t + w - WIN;
    bool valid = (pos >= 0) && (pos < T_LEN);
    int pc = min(max(pos, 0), T_LEN - 1);
    const bf16* krow = qkv + (size_t)(base + pc) * 1536 + 512 + h * 64 + dsub * 8;
    bf16x8 k8 = *(const bf16x8*)krow;
    float acc = 0.f;
#pragma unroll
    for (int e = 0; e < 8; ++e) acc += (float)q8[e] * (float)k8[e];
    // reduce across the 8 lanes of this item (lanes are aligned: item*8..item*8+7)
    acc += __shfl_xor(acc, 1);
    acc += __shfl_xor(acc, 2);
    acc += __shfl_xor(acc, 4);
    s[w] = valid ? acc * scale : -1e30f;
  }

  float m = -1e30f;
#pragma unroll
  for (int w = 0; w < WSZ; ++w) m = fmaxf(m, s[w]);
  float sum = 0.f;
#pragma unroll
  for (int w = 0; w < WSZ; ++w) {
    float p = __expf(s[w] - m);
    s[w] = p;
    sum += p;
  }
  float inv = 1.f / sum;

  float o[8];
#pragma unroll
  for (int e = 0; e < 8; ++e) o[e] = 0.f;
#pragma unroll
  for (int w = 0; w < WSZ; ++w) {
    int pos = t + w - WIN;
    int pc = min(max(pos, 0), T_LEN - 1);
    const bf16* vrow = qkv + (size_t)(base + pc) * 1536 + 1024 + h * 64 + dsub * 8;
    bf16x8 v8 = *(const bf16x8*)vrow;
    float pw = s[w];
#pragma unroll
    for (int e = 0; e < 8; ++e) o[e] += pw * (float)v8[e];
  }

  bf16x8 ov;
#pragma unroll
  for (int e = 0; e < 8; ++e) ov[e] = (bf16)(o[e] * inv);
  *(bf16x8*)(aout + (size_t)bt * 512 + h * 64 + dsub * 8) = ov;
}

// ---- in-place LayerNorm, one wave per 512-wide row ----
__global__ __launch_bounds__(256) void ln_kernel(float* __restrict__ y,
                                                 const float* __restrict__ gamma,
                                                 const float* __restrict__ beta) {
  const int tid = threadIdx.x;
  const int l = tid & 63;
  const int row = blockIdx.x * 4 + (tid >> 6);
  float* p = y + (size_t)row * 512 + l * 8;
  float4 a = *(const float4*)(p);
  float4 b = *(const float4*)(p + 4);
  float s = a.x + a.y + a.z + a.w + b.x + b.y + b.z + b.w;
  float ss = a.x * a.x + a.y * a.y + a.z * a.z + a.w * a.w +
             b.x * b.x + b.y * b.y + b.z * b.z + b.w * b.w;
#pragma unroll
  for (int off = 32; off > 0; off >>= 1) {
    s += __shfl_xor(s, off);
    ss += __shfl_xor(ss, off);
  }
  float mu = s * (1.f / 512.f);
  float var = ss * (1.f / 512.f) - mu * mu;
  float rs = rsqrtf(var + 1e-5f);
  float4 g0 = *(const float4*)(gamma + l * 8);
  float4 g1 = *(const float4*)(gamma + l * 8 + 4);
  float4 b0 = *(const float4*)(beta + l * 8);
  float4 b1 = *(const float4*)(beta + l * 8 + 4);
  float4 o0, o1;
  o0.x = g0.x * (a.x - mu) * rs + b0.x;
  o0.y = g0.y * (a.y - mu) * rs + b0.y;
  o0.z = g0.z * (a.z - mu) * rs + b0.z;
  o0.w = g0.w * (a.w - mu) * rs + b0.w;
  o1.x = g1.x * (b.x - mu) * rs + b1.x;
  o1.y = g1.y * (b.y - mu) * rs + b1.y;
  o1.z = g1.z * (b.z - mu) * rs + b1.z;
  o1.w = g1.w * (b.w - mu) * rs + b1.w;
  *(float4*)(p) = o0;
  *(float4*)(p + 4) = o1;
}

extern "C" void kernel_launch(void* const* d_in, const int* in_sizes, int n_in,
                              void* d_out, int out_size, void* d_ws, size_t ws_size,
                              hipStream_t stream) {
  const float* x  = (const float*)d_in[0];
  const float* Wq = (const float*)d_in[1];
  const float* Wk = (const float*)d_in[2];
  const float* Wv = (const float*)d_in[3];
  const float* Wp = (const float*)d_in[4];
  const float* g  = (const float*)d_in[5];
  const float* be = (const float*)d_in[6];
  float* out = (float*)d_out;

  char* ws = (char*)d_ws;
  bf16* xb   = (bf16*)(ws);                                   // 8,388,608 B
  bf16* wqkv = (bf16*)(ws + 8388608);                         // 1,572,864 B
  bf16* wpb  = (bf16*)(ws + 8388608 + 1572864);               //   524,288 B
  bf16* qkv  = (bf16*)(ws + 8388608 + 1572864 + 524288);      // 25,165,824 B
  bf16* aout = (bf16*)(ws + 8388608 + 1572864 + 524288 + 25165824);  // 8,388,608 B

  cast_x_kernel<<<2048, 256, 0, stream>>>(x, xb);
  cast_w_kernel<<<512, 256, 0, stream>>>(Wq, Wk, Wv, Wp, wqkv, wpb);
  // QKV: M=8192, N=1536 -> 64 x 12 tiles
  gemm_bt_kernel<0><<<64 * 12, 256, 0, stream>>>(xb, wqkv, qkv, 1536, nullptr, nullptr, 12);
  attn_kernel<<<2048, 256, 0, stream>>>(qkv, aout);
  // proj + residual: M=8192, N=512 -> 64 x 4 tiles
  gemm_bt_kernel<1><<<64 * 4, 256, 0, stream>>>(aout, wpb, nullptr, 0, out, x, 4);
  ln_kernel<<<2048, 256, 0, stream>>>(out, g, be);
}

// Round 3
// 82.106 us; speedup vs baseline: 2.0127x; 1.3949x over previous
//
#include <hip/hip_runtime.h>
#include <hip/hip_bf16.h>
#include <stdint.h>

typedef __bf16 bf16;
typedef __attribute__((ext_vector_type(8))) __bf16 bf16x8;
typedef __attribute__((ext_vector_type(4))) float f32x4;

#define GLOAD16(gsrc, ldst)                                              \
  __builtin_amdgcn_global_load_lds(                                      \
      (const __attribute__((address_space(1))) unsigned int*)(gsrc),     \
      (__attribute__((address_space(3))) unsigned int*)(ldst), 16, 0, 0)

static constexpr int T_LEN = 4096;
static constexpr int WIN = 16;
static constexpr int WSZ = 2 * WIN + 1;  // 33

__device__ __forceinline__ bf16x8 cvt8(float4 a, float4 b) {
  bf16x8 o;
  o[0] = (bf16)a.x; o[1] = (bf16)a.y; o[2] = (bf16)a.z; o[3] = (bf16)a.w;
  o[4] = (bf16)b.x; o[5] = (bf16)b.y; o[6] = (bf16)b.z; o[7] = (bf16)b.w;
  return o;
}

// ---- cast x (fp32 -> bf16), 8 elems/thread, 8192*512 total ----
__global__ __launch_bounds__(256) void cast_x_kernel(const float* __restrict__ x,
                                                     bf16* __restrict__ xb) {
  int i = blockIdx.x * 256 + threadIdx.x;  // 524288 threads
  const float4* s4 = (const float4*)x + (size_t)i * 2;
  ((bf16x8*)xb)[i] = cvt8(s4[0], s4[1]);
}

// ---- cast + pack Wq,Wk,Wv -> wqkv[1536][512], Wp -> wpb[512][512] ----
__global__ __launch_bounds__(256) void cast_w_kernel(const float* __restrict__ wq,
                                                     const float* __restrict__ wk,
                                                     const float* __restrict__ wv,
                                                     const float* __restrict__ wp,
                                                     bf16* __restrict__ wqkv,
                                                     bf16* __restrict__ wpb) {
  int i = blockIdx.x * 256 + threadIdx.x;  // 131072 threads (4 * 512*512/8)
  int which = i >> 15;                     // 32768 groups of 8 per matrix
  int j = i & 32767;
  const float* src = (which == 0) ? wq : (which == 1) ? wk : (which == 2) ? wv : wp;
  bf16* dst = (which < 3) ? (wqkv + (size_t)which * 512 * 512) : wpb;
  const float4* s4 = (const float4*)src + (size_t)j * 2;
  ((bf16x8*)dst)[j] = cvt8(s4[0], s4[1]);
}

// ---- GEMM: C[m][n] = sum_k A[m][k] * Bw[n][k]  (A: Mx512 bf16, Bw: Nx512 bf16 row-major)
// EPI=0: store bf16 into Cb with leading dim ldc
// EPI=1: store fp32 Cf[m*512+n] = acc + Xres[m*512+n]   (residual)
template <int EPI>
__global__ __launch_bounds__(256) void gemm_bt_kernel(const bf16* __restrict__ A,
                                                      const bf16* __restrict__ Bw,
                                                      bf16* __restrict__ Cb, int ldc,
                                                      float* __restrict__ Cf,
                                                      const float* __restrict__ Xres,
                                                      int NB) {
  constexpr int K = 512, BK = 32;
  __shared__ __align__(16) bf16 As[128 * BK];
  __shared__ __align__(16) bf16 Bs[128 * BK];
  const int tid = threadIdx.x;
  const int l = tid & 63;
  const int w = tid >> 6;
  const int m0 = (blockIdx.x / NB) * 128;
  const int n0 = (blockIdx.x % NB) * 128;
  const int arow = tid >> 2;
  const int acol = (tid & 3) * 8;
  const bf16* Ag = A + (size_t)(m0 + arow) * K + acol;
  const bf16* Bg = Bw + (size_t)(n0 + arow) * K + acol;

  const f32x4 zero = {0.f, 0.f, 0.f, 0.f};
  f32x4 acc[4][4];
#pragma unroll
  for (int i = 0; i < 4; ++i)
#pragma unroll
    for (int j = 0; j < 4; ++j) acc[i][j] = zero;

  const int wm = (w >> 1) * 64;
  const int wn = (w & 1) * 64;
  const int frow = l & 15;
  const int fcol = (l >> 4) * 8;

  for (int k0 = 0; k0 < K; k0 += BK) {
    GLOAD16(Ag + k0,           &As[tid * 8]);
    GLOAD16(Ag + 64 * K + k0,  &As[tid * 8 + 2048]);
    GLOAD16(Bg + k0,           &Bs[tid * 8]);
    GLOAD16(Bg + 64 * K + k0,  &Bs[tid * 8 + 2048]);
    __syncthreads();
    bf16x8 af[4], bfr[4];
#pragma unroll
    for (int mi = 0; mi < 4; ++mi)
      af[mi] = *(const bf16x8*)&As[(wm + mi * 16 + frow) * BK + fcol];
#pragma unroll
    for (int ni = 0; ni < 4; ++ni)
      bfr[ni] = *(const bf16x8*)&Bs[(wn + ni * 16 + frow) * BK + fcol];
#pragma unroll
    for (int mi = 0; mi < 4; ++mi)
#pragma unroll
      for (int ni = 0; ni < 4; ++ni)
        acc[mi][ni] = __builtin_amdgcn_mfma_f32_16x16x32_bf16(af[mi], bfr[ni], acc[mi][ni], 0, 0, 0);
    __syncthreads();
  }

  // C/D layout: col = lane&15, row = (lane>>4)*4 + reg
  const int r0 = (l >> 4) * 4;
  const int c0 = l & 15;
#pragma unroll
  for (int mi = 0; mi < 4; ++mi) {
#pragma unroll
    for (int ni = 0; ni < 4; ++ni) {
      int row = m0 + wm + mi * 16 + r0;
      int col = n0 + wn + ni * 16 + c0;
#pragma unroll
      for (int r = 0; r < 4; ++r) {
        if (EPI == 0) {
          Cb[(size_t)(row + r) * ldc + col] = (bf16)acc[mi][ni][r];
        } else {
          size_t o = (size_t)(row + r) * 512 + col;
          Cf[o] = acc[mi][ni][r] + Xres[o];
        }
      }
    }
  }
}

// ---- local attention, LDS-tiled ----
// Block = 256 threads: one (b,h) x 64 t-rows. K,V staged in LDS (bf16,
// 96 positions x 64 dims, row stride 72 to balance banks).
// Thread = (row r = tid>>2, 16-dim slice ds = tid&3).
static constexpr int TC = 64;       // t-rows per block
static constexpr int NPOS = 96;     // TC + 2*WIN halo
static constexpr int KSTRIDE = 72;  // padded LDS row stride (bf16 elems)

__global__ __launch_bounds__(256) void attn_kernel(const bf16* __restrict__ qkv,
                                                   bf16* __restrict__ aout) {
  __shared__ __align__(16) bf16 Kh[NPOS * KSTRIDE];
  __shared__ __align__(16) bf16 Vh[NPOS * KSTRIDE];

  const int tid = threadIdx.x;
  const int bid = blockIdx.x;          // 1024 = 2 * 8 * 64
  const int chunk = bid & 63;
  const int h = (bid >> 6) & 7;
  const int b = bid >> 9;
  const int t0 = chunk * TC;
  const int base = b * T_LEN;

  // ---- stage K,V: 96 positions x 64 dims, clamped ----
  for (int c = tid; c < NPOS * 8; c += 256) {  // 768 chunks of 8 bf16
    int p = c >> 3;
    int d8 = (c & 7) * 8;
    int pg = min(max(t0 - WIN + p, 0), T_LEN - 1);
    const bf16* kr = qkv + (size_t)(base + pg) * 1536 + 512 + h * 64 + d8;
    const bf16* vr = qkv + (size_t)(base + pg) * 1536 + 1024 + h * 64 + d8;
    *(bf16x8*)&Kh[p * KSTRIDE + d8] = *(const bf16x8*)kr;
    *(bf16x8*)&Vh[p * KSTRIDE + d8] = *(const bf16x8*)vr;
  }
  __syncthreads();

  const int r = tid >> 2;        // row within chunk [0,64)
  const int ds = tid & 3;        // 16-dim slice
  const int t = t0 + r;
  const float scale = 0.125f;    // 64^-0.5

  // Q slice -> 16 f32 regs
  const bf16* qrow = qkv + (size_t)(base + t) * 1536 + h * 64 + ds * 16;
  bf16x8 qa = ((const bf16x8*)qrow)[0];
  bf16x8 qb = ((const bf16x8*)qrow)[1];
  float qf[16];
#pragma unroll
  for (int e = 0; e < 8; ++e) { qf[e] = (float)qa[e]; qf[8 + e] = (float)qb[e]; }

  // ---- scores ----
  float s[WSZ];
#pragma unroll
  for (int w = 0; w < WSZ; ++w) {
    const bf16* kp = &Kh[(r + w) * KSTRIDE + ds * 16];
    bf16x8 ka = ((const bf16x8*)kp)[0];
    bf16x8 kb = ((const bf16x8*)kp)[1];
    float acc = 0.f;
#pragma unroll
    for (int e = 0; e < 8; ++e) acc += qf[e] * (float)ka[e];
#pragma unroll
    for (int e = 0; e < 8; ++e) acc += qf[8 + e] * (float)kb[e];
    acc += __shfl_xor(acc, 1);
    acc += __shfl_xor(acc, 2);
    int pos = t - WIN + w;
    bool valid = (pos >= 0) && (pos < T_LEN);
    s[w] = valid ? acc * scale : -1e30f;
  }

  // ---- softmax over 33 ----
  float m = -1e30f;
#pragma unroll
  for (int w = 0; w < WSZ; ++w) m = fmaxf(m, s[w]);
  float sum = 0.f;
#pragma unroll
  for (int w = 0; w < WSZ; ++w) {
    float p = __expf(s[w] - m);
    s[w] = p;
    sum += p;
  }
  float inv = 1.f / sum;

  // ---- PV ----
  float o[16];
#pragma unroll
  for (int e = 0; e < 16; ++e) o[e] = 0.f;
#pragma unroll
  for (int w = 0; w < WSZ; ++w) {
    const bf16* vp = &Vh[(r + w) * KSTRIDE + ds * 16];
    bf16x8 va = ((const bf16x8*)vp)[0];
    bf16x8 vb = ((const bf16x8*)vp)[1];
    float pw = s[w];
#pragma unroll
    for (int e = 0; e < 8; ++e) o[e] += pw * (float)va[e];
#pragma unroll
    for (int e = 0; e < 8; ++e) o[8 + e] += pw * (float)vb[e];
  }

  bf16x8 o0, o1;
#pragma unroll
  for (int e = 0; e < 8; ++e) {
    o0[e] = (bf16)(o[e] * inv);
    o1[e] = (bf16)(o[8 + e] * inv);
  }
  bf16* orow = aout + (size_t)(base + t) * 512 + h * 64 + ds * 16;
  ((bf16x8*)orow)[0] = o0;
  ((bf16x8*)orow)[1] = o1;
}

// ---- in-place LayerNorm, one wave per 512-wide row ----
__global__ __launch_bounds__(256) void ln_kernel(float* __restrict__ y,
                                                 const float* __restrict__ gamma,
                                                 const float* __restrict__ beta) {
  const int tid = threadIdx.x;
  const int l = tid & 63;
  const int row = blockIdx.x * 4 + (tid >> 6);
  float* p = y + (size_t)row * 512 + l * 8;
  float4 a = *(const float4*)(p);
  float4 b = *(const float4*)(p + 4);
  float s = a.x + a.y + a.z + a.w + b.x + b.y + b.z + b.w;
  float ss = a.x * a.x + a.y * a.y + a.z * a.z + a.w * a.w +
             b.x * b.x + b.y * b.y + b.z * b.z + b.w * b.w;
#pragma unroll
  for (int off = 32; off > 0; off >>= 1) {
    s += __shfl_xor(s, off);
    ss += __shfl_xor(ss, off);
  }
  float mu = s * (1.f / 512.f);
  float var = ss * (1.f / 512.f) - mu * mu;
  float rs = rsqrtf(var + 1e-5f);
  float4 g0 = *(const float4*)(gamma + l * 8);
  float4 g1 = *(const float4*)(gamma + l * 8 + 4);
  float4 b0 = *(const float4*)(beta + l * 8);
  float4 b1 = *(const float4*)(beta + l * 8 + 4);
  float4 o0, o1;
  o0.x = g0.x * (a.x - mu) * rs + b0.x;
  o0.y = g0.y * (a.y - mu) * rs + b0.y;
  o0.z = g0.z * (a.z - mu) * rs + b0.z;
  o0.w = g0.w * (a.w - mu) * rs + b0.w;
  o1.x = g1.x * (b.x - mu) * rs + b1.x;
  o1.y = g1.y * (b.y - mu) * rs + b1.y;
  o1.z = g1.z * (b.z - mu) * rs + b1.z;
  o1.w = g1.w * (b.w - mu) * rs + b1.w;
  *(float4*)(p) = o0;
  *(float4*)(p + 4) = o1;
}

extern "C" void kernel_launch(void* const* d_in, const int* in_sizes, int n_in,
                              void* d_out, int out_size, void* d_ws, size_t ws_size,
                              hipStream_t stream) {
  const float* x  = (const float*)d_in[0];
  const float* Wq = (const float*)d_in[1];
  const float* Wk = (const float*)d_in[2];
  const float* Wv = (const float*)d_in[3];
  const float* Wp = (const float*)d_in[4];
  const float* g  = (const float*)d_in[5];
  const float* be = (const float*)d_in[6];
  float* out = (float*)d_out;

  char* ws = (char*)d_ws;
  bf16* xb   = (bf16*)(ws);                                   // 8,388,608 B
  bf16* wqkv = (bf16*)(ws + 8388608);                         // 1,572,864 B
  bf16* wpb  = (bf16*)(ws + 8388608 + 1572864);               //   524,288 B
  bf16* qkv  = (bf16*)(ws + 8388608 + 1572864 + 524288);      // 25,165,824 B
  bf16* aout = (bf16*)(ws + 8388608 + 1572864 + 524288 + 25165824);  // 8,388,608 B

  cast_x_kernel<<<2048, 256, 0, stream>>>(x, xb);
  cast_w_kernel<<<512, 256, 0, stream>>>(Wq, Wk, Wv, Wp, wqkv, wpb);
  // QKV: M=8192, N=1536 -> 64 x 12 tiles
  gemm_bt_kernel<0><<<64 * 12, 256, 0, stream>>>(xb, wqkv, qkv, 1536, nullptr, nullptr, 12);
  // attn: blocks = B(2) * H(8) * T/TC(64) = 1024
  attn_kernel<<<1024, 256, 0, stream>>>(qkv, aout);
  // proj + residual: M=8192, N=512 -> 64 x 4 tiles
  gemm_bt_kernel<1><<<64 * 4, 256, 0, stream>>>(aout, wpb, nullptr, 0, out, x, 4);
  ln_kernel<<<2048, 256, 0, stream>>>(out, g, be);
}